// Round 1
// 632.481 us; speedup vs baseline: 1.0014x; 1.0014x over previous
//
#include <hip/hip_runtime.h>
#include <math.h>

// Problem constants: x shape (B=4, C=8, D=16, H=256, W=256), k=3x3x3, stride 1, pad 1.
#define BC 32
#define DD 16
#define HH 256
#define WW 256
#define PLANE (HH * WW)              // 65536
#define CH_ELEMS (DD * PLANE)        // 1048576
#define COORD_ELEMS (BC * 3 * CH_ELEMS)  // 100663296
#define TS 68                        // LDS row stride (66 used + pad, 16B-aligned rows)

typedef float vf4 __attribute__((ext_vector_type(4)));

// ---------------- Pass 1: per-channel max ----------------
__global__ __launch_bounds__(256) void chmax_part(const float* __restrict__ x,
                                                  float* __restrict__ part) {
    const int ch = blockIdx.y;
    const int tid = threadIdx.x;
    const float4* p4 = (const float4*)(x + (size_t)ch * CH_ELEMS) + (size_t)blockIdx.x * 4096;
    float m = -3.402823466e38f;
#pragma unroll
    for (int i = 0; i < 16; ++i) {
        float4 v = p4[tid + i * 256];
        m = fmaxf(m, fmaxf(fmaxf(v.x, v.y), fmaxf(v.z, v.w)));
    }
#pragma unroll
    for (int off = 32; off > 0; off >>= 1)
        m = fmaxf(m, __shfl_down(m, off, 64));
    __shared__ float sm[4];
    if ((tid & 63) == 0) sm[tid >> 6] = m;
    __syncthreads();
    if (tid == 0)
        part[ch * 64 + blockIdx.x] = fmaxf(fmaxf(sm[0], sm[1]), fmaxf(sm[2], sm[3]));
}

__global__ __launch_bounds__(64) void chmax_final(const float* __restrict__ part,
                                                  float* __restrict__ mx) {
    const int ch = blockIdx.x, tid = threadIdx.x;
    float m = part[ch * 64 + tid];
#pragma unroll
    for (int off = 32; off > 0; off >>= 1)
        m = fmaxf(m, __shfl_down(m, off, 64));
    if (tid == 0) mx[ch] = m;
}

// ---------------- Pass 2: fused conv-soft-argmax ----------------
// Block: 256 threads. Tile: 16 h x 64 w, full D loop, one channel (blockIdx.z).
// Thread (hl = tid>>4, wb = (tid&15)*4) owns 4 consecutive w outputs for all d.
//
// Software pipeline (T14 issue-early / write-late, depth 2):
//   iter I: LDS-write slice I+1 from prefetch regs -> issue loads for slice I+2
//           -> compute slice I -> emit depth I-2 -> one barrier.
// Global-load latency is hidden under ~2 full compute phases; loads cross the
// barriers legally (register destinations, no LDS dependency).
__global__ __launch_bounds__(256) void csam3d_main(const float* __restrict__ xin_all,
                                                   const float* __restrict__ mx,
                                                   float* __restrict__ out) {
    const int ch = blockIdx.z;
    const int h0 = blockIdx.y * 16;
    const int w0 = blockIdx.x * 64;
    const int tid = threadIdx.x;
    const float cmax = mx[ch];
    const float* __restrict__ xin = xin_all + (size_t)ch * CH_ELEMS;

    float* __restrict__ outz = out + (size_t)(ch * 3 + 0) * CH_ELEMS;
    float* __restrict__ outx = out + (size_t)(ch * 3 + 1) * CH_ELEMS;
    float* __restrict__ outy = out + (size_t)(ch * 3 + 2) * CH_ELEMS;
    float* __restrict__ outv = out + COORD_ELEMS + (size_t)ch * CH_ELEMS;

    __shared__ __align__(16) float eS[2][18 * TS];  // exp(x - cmax), zero-padded halo
    __shared__ __align__(16) float vS[2][18 * TS];  // e * x

    const int hl = tid >> 4;          // 0..15
    const int wb = (tid & 15) << 2;   // 0,4,...,60

    // -------- per-thread staging metadata, computed ONCE (was recomputed 18x) -----
    // slice linearization: s5 = tid + it*256 over 18 rows x 66 cols
    int soff[5];   // global plane offset (clamped-safe when invalid)
    int slds[5];   // LDS word offset
    bool sval[5];  // in-plane validity (h/w bounds AND s5 < 18*66)
#pragma unroll
    for (int it = 0; it < 5; ++it) {
        int s5 = tid + it * 256;
        int lh = s5 / 66;
        int lw = s5 - lh * 66;
        int gh = h0 + lh - 1;
        int gw = w0 + lw - 1;
        bool v = (s5 < 18 * 66) && ((unsigned)gh < (unsigned)HH) && ((unsigned)gw < (unsigned)WW);
        sval[it] = v;
        soff[it] = v ? (gh * WW + gw) : 0;   // safe fallback addr; value masked later
        slds[it] = lh * TS + lw;
    }

    float pfA[5], pfB[5];             // 2-deep prefetch registers (static names, rule #20)

    // 3-slot ring of per-slice 2D window stats, 4 w-outputs each
    float s2[3][4], mx2[3][4], my2[3][4], sv2[3][4];

// Issue unconditional (address-clamped) global loads for input depth DIN into PF.
#define PREFETCH(DIN, PF) do {                                                \
    const float* xp_ = xin + (size_t)(DIN) * PLANE;                           \
    _Pragma("unroll")                                                         \
    for (int it = 0; it < 5; ++it) PF[it] = xp_[soff[it]];                    \
} while (0)

// Convert prefetched raw values and write slice into LDS buffer BUF.
// ZERO (compile-time) forces an all-zero slice (out-of-range depth).
#define WRITESLICE(BUF, PF, ZERO) do {                                        \
    float* eb_ = eS[BUF];                                                     \
    float* vb_ = vS[BUF];                                                     \
    _Pragma("unroll")                                                         \
    for (int it = 0; it < 5; ++it) {                                          \
        if (it < 4 || tid < 18 * 66 - 1024) {  /* s5 < 1188 (static for it<4) */ \
            float xv_ = PF[it];                                               \
            float ev_ = (sval[it] && !(ZERO)) ? __expf(xv_ - cmax) : 0.f;     \
            eb_[slds[it]] = ev_;                                              \
            vb_[slds[it]] = ev_ * xv_;                                        \
        }                                                                     \
    }                                                                         \
} while (0)

#define LDROW(PTR) do {                                                       \
    float4 a_ = *(const float4*)(PTR);                                        \
    float2 b_ = *(const float2*)((PTR) + 4);                                  \
    v0 = a_.x; v1 = a_.y; v2 = a_.z; v3 = a_.w; v4 = b_.x; v5 = b_.y;         \
} while (0)

// Compute 2D (h,w) window stats for slice I into ring slot SC. (unchanged numerics)
#define CSLICE(I, SC) do {                                                    \
    const float* eb_ = eS[(I) & 1] + hl * TS + wb;                            \
    const float* vb_ = vS[(I) & 1] + hl * TS + wb;                            \
    float v0, v1, v2, v3, v4, v5;                                             \
    LDROW(eb_);                                                               \
    float c0 = v0, c1 = v1, c2 = v2, c3 = v3, c4 = v4, c5 = v5;               \
    float d0 = -v0, d1 = -v1, d2 = -v2, d3 = -v3, d4 = -v4, d5 = -v5;         \
    LDROW(eb_ + TS);                                                          \
    c0 += v0; c1 += v1; c2 += v2; c3 += v3; c4 += v4; c5 += v5;               \
    LDROW(eb_ + 2 * TS);                                                      \
    c0 += v0; c1 += v1; c2 += v2; c3 += v3; c4 += v4; c5 += v5;               \
    d0 += v0; d1 += v1; d2 += v2; d3 += v3; d4 += v4; d5 += v5;               \
    LDROW(vb_);                                                               \
    float g0 = v0, g1 = v1, g2 = v2, g3 = v3, g4 = v4, g5 = v5;               \
    LDROW(vb_ + TS);                                                          \
    g0 += v0; g1 += v1; g2 += v2; g3 += v3; g4 += v4; g5 += v5;               \
    LDROW(vb_ + 2 * TS);                                                      \
    g0 += v0; g1 += v1; g2 += v2; g3 += v3; g4 += v4; g5 += v5;               \
    s2[SC][0] = c0 + c1 + c2;  s2[SC][1] = c1 + c2 + c3;                      \
    s2[SC][2] = c2 + c3 + c4;  s2[SC][3] = c3 + c4 + c5;                      \
    mx2[SC][0] = c2 - c0; mx2[SC][1] = c3 - c1;                               \
    mx2[SC][2] = c4 - c2; mx2[SC][3] = c5 - c3;                               \
    my2[SC][0] = d0 + d1 + d2;  my2[SC][1] = d1 + d2 + d3;                    \
    my2[SC][2] = d2 + d3 + d4;  my2[SC][3] = d3 + d4 + d5;                    \
    sv2[SC][0] = g0 + g1 + g2;  sv2[SC][1] = g1 + g2 + g3;                    \
    sv2[SC][2] = g2 + g3 + g4;  sv2[SC][3] = g3 + g4 + g5;                    \
} while (0)

// Emit output depth dout = I-2 combining ring slots SA (d-1), SB (d), SC (d+1).
#define EMIT(I, SA, SB, SC) do {                                              \
    const int dout_ = (I) - 2;                                                \
    vf4 oz, ox, oy, ov;                                                       \
    _Pragma("unroll")                                                         \
    for (int k = 0; k < 4; ++k) {                                             \
        float S  = s2[SA][k] + s2[SB][k] + s2[SC][k];                         \
        float Mz = s2[SC][k] - s2[SA][k];                                     \
        float Mx = mx2[SA][k] + mx2[SB][k] + mx2[SC][k];                      \
        float My = my2[SA][k] + my2[SB][k] + my2[SC][k];                      \
        float Sv = sv2[SA][k] + sv2[SB][k] + sv2[SC][k];                      \
        float inv = __builtin_amdgcn_rcpf(S + 1e-8f);                         \
        oz[k] = Mz * inv + (float)dout_;                                      \
        ox[k] = Mx * inv + (float)(w0 + wb + k);                              \
        oy[k] = My * inv + (float)(h0 + hl);                                  \
        ov[k] = Sv * inv;                                                     \
    }                                                                         \
    size_t off_ = (size_t)dout_ * PLANE + (size_t)(h0 + hl) * WW + (w0 + wb); \
    __builtin_nontemporal_store(oz, (vf4*)(outz + off_));                     \
    __builtin_nontemporal_store(ox, (vf4*)(outx + off_));                     \
    __builtin_nontemporal_store(oy, (vf4*)(outy + off_));                     \
    __builtin_nontemporal_store(ov, (vf4*)(outv + off_));                     \
} while (0)

// One pipelined step. All guards are compile-time (full unroll below).
//   write slice I+1 from PF (loaded 2 iters ago) -> issue loads for slice I+2
//   -> compute slice I -> emit depth I-2 -> barrier.
// Hazards: WRITESLICE(buf[(I+1)&1]) vs CSLICE(I-1) reads -> prev iter's barrier.
//          CSLICE(I) reads buf[I&1] written last iter -> prev iter's barrier.
#define STEP(I, SC, SA, SB, PF) do {                                          \
    if ((I) < 17) WRITESLICE((I + 1) & 1, PF, (I) >= 16);                     \
    if ((I) <= 13) PREFETCH((I) + 2, PF);  /* din = I+1, used at iter I+2 */  \
    CSLICE(I, SC);                                                            \
    if ((I) >= 2) EMIT(I, SA, SB, SC);                                        \
    __syncthreads();                                                          \
} while (0)

    // Prologue: issue loads for slices 1,2 (din 0,1); zero buf0 (slice 0, din=-1).
    PREFETCH(0, pfA);
    PREFETCH(1, pfB);
    for (int i = tid; i < 18 * TS; i += 256) {
        eS[0][i] = 0.f;
        vS[0][i] = 0.f;
    }
    __syncthreads();

    // Fully unrolled: iter I consumes pf[I&1]; slot SC = I%3, SA = (I-2)%3, SB = (I-1)%3.
    STEP(0,  0, 1, 2, pfA);
    STEP(1,  1, 2, 0, pfB);
    STEP(2,  2, 0, 1, pfA);
    STEP(3,  0, 1, 2, pfB);
    STEP(4,  1, 2, 0, pfA);
    STEP(5,  2, 0, 1, pfB);
    STEP(6,  0, 1, 2, pfA);
    STEP(7,  1, 2, 0, pfB);
    STEP(8,  2, 0, 1, pfA);
    STEP(9,  0, 1, 2, pfB);
    STEP(10, 1, 2, 0, pfA);
    STEP(11, 2, 0, 1, pfB);
    STEP(12, 0, 1, 2, pfA);
    STEP(13, 1, 2, 0, pfB);
    STEP(14, 2, 0, 1, pfA);
    STEP(15, 0, 1, 2, pfB);
    STEP(16, 1, 2, 0, pfA);
    STEP(17, 2, 0, 1, pfB);
}

extern "C" void kernel_launch(void* const* d_in, const int* in_sizes, int n_in,
                              void* d_out, int out_size, void* d_ws, size_t ws_size,
                              hipStream_t stream) {
    const float* x = (const float*)d_in[0];
    float* out = (float*)d_out;
    float* part = (float*)d_ws;      // 2048 floats
    float* mx = part + 2048;         // 32 floats

    chmax_part<<<dim3(64, 32), 256, 0, stream>>>(x, part);
    chmax_final<<<32, 64, 0, stream>>>(part, mx);
    csam3d_main<<<dim3(4, 16, 32), 256, 0, stream>>>(x, mx, out);
}